// Round 6
// baseline (168.192 us; speedup 1.0000x reference)
//
#include <hip/hip_runtime.h>
#include <float.h>

#define W  128
#define NB 50
#define NPASS 6   // phase-5 replication: calibration to make the mtf dispatch
                  // visible in rocprof top-5 (fills are ~63us; kernel must exceed that).
                  // Idempotent: every pass writes identical values to identical addresses.

__global__ __launch_bounds__(256) void mtf_kernel(const float* __restrict__ X,
                                                  float* __restrict__ out) {
    __shared__ int   bins[W];
    __shared__ int   hist[NB * NB];
    __shared__ int   rowsum[NB];
    __shared__ float probs[NB * NB];
    __shared__ float redmin[4], redmax[4];

    const int tid = threadIdx.x;
    const int s   = blockIdx.x;
    const float* xrow = X + (size_t)s * W;

    // ---- Phase 1: load + min/max reduction (wave = 64 lanes) ----
    float v = 0.0f;
    float vmin = FLT_MAX, vmax = -FLT_MAX;
    if (tid < W) { v = xrow[tid]; vmin = v; vmax = v; }
    #pragma unroll
    for (int off = 32; off >= 1; off >>= 1) {
        vmin = fminf(vmin, __shfl_down(vmin, off, 64));
        vmax = fmaxf(vmax, __shfl_down(vmax, off, 64));
    }
    if ((tid & 63) == 0) { redmin[tid >> 6] = vmin; redmax[tid >> 6] = vmax; }

    for (int i = tid; i < NB * NB; i += 256) hist[i] = 0;
    if (tid < NB) rowsum[tid] = 0;
    __syncthreads();

    const float mn = fminf(fminf(redmin[0], redmin[1]), fminf(redmin[2], redmin[3]));
    const float mx = fmaxf(fmaxf(redmax[0], redmax[1]), fmaxf(redmax[2], redmax[3]));
    const float d  = (mx - mn) + 1e-6f;   // matches (X_max - X_min + EPS) in fp32

    // ---- Phase 2: bucketize (searchsorted side='left': #{edge < x}) ----
    if (tid < W) {
        float q   = (v - mn) / d;
        float xsc = q * 2.0f - 1.0f;
        double xd = (double)xsc;
        int b = 0;
        #pragma unroll
        for (int k = 1; k <= NB - 1; ++k) {
            double bk = -1.0 + 0.04 * (double)k;   // linspace inner edges (fp64)
            b += (bk < xd) ? 1 : 0;
        }
        bins[tid] = b;
    }
    __syncthreads();

    // ---- Phase 3: transition histogram + row sums (LDS atomics) ----
    if (tid < W - 1) {
        int bi = bins[tid], bj = bins[tid + 1];
        atomicAdd(&hist[bi * NB + bj], 1);
        atomicAdd(&rowsum[bi], 1);
    }
    __syncthreads();

    // ---- Phase 4: row-normalize (exact fp32 division, empty-row guard) ----
    for (int i = tid; i < NB * NB; i += 256) {
        int rs = rowsum[i / NB];
        probs[i] = (float)hist[i] / (float)(rs == 0 ? 1 : rs);
    }
    __syncthreads();

    // ---- Phase 5 x NPASS: gather + contiguous ascending stores ----
    float* orow = out + (size_t)s * W * W;
    const int wv   = tid >> 6;
    const int lane = tid & 63;
    const int c4   = (lane & 31) * 4;
    const int half = lane >> 5;
    const int b0 = bins[c4], b1 = bins[c4 + 1], b2 = bins[c4 + 2], b3 = bins[c4 + 3];
    for (int p = 0; p < NPASS; ++p) {
        #pragma unroll
        for (int it = 0; it < 16; ++it) {
            int row = (wv << 5) + (it << 1) + half;
            int rb  = bins[row] * NB;
            float4 o;
            o.x = probs[rb + b0];
            o.y = probs[rb + b1];
            o.z = probs[rb + b2];
            o.w = probs[rb + b3];
            *(float4*)(orow + row * W + c4) = o;
        }
        // keep each pass's stores observable (prevents cross-pass dead-store elim)
        asm volatile("" ::: "memory");
    }
}

extern "C" void kernel_launch(void* const* d_in, const int* in_sizes, int n_in,
                              void* d_out, int out_size, void* d_ws, size_t ws_size,
                              hipStream_t stream) {
    const float* X = (const float*)d_in[0];
    float* out = (float*)d_out;
    int S = in_sizes[0] / W;             // 256*6 = 1536 series
    mtf_kernel<<<dim3(S), dim3(256), 0, stream>>>(X, out);
}

// Round 7
// 105.310 us; speedup vs baseline: 1.5971x; 1.5971x over previous
//
#include <hip/hip_runtime.h>
#include <float.h>

#define W  128
#define NB 50

// ROOFLINE-verified monolith (R3 structure).
// Calibration (R6, NPASS=6 replication) measured this kernel's store path at
// 7.17 TB/s = 89.7% of the 8 TB/s HBM spec peak (above the 6.3 TB/s "achievable"
// ceiling and above the harness fill's own 6.4 TB/s). Single-pass kernel time
// ~20.6 us vs a 14.0 us pure-write floor; the remaining dur_us is harness-fixed
// (63.5 us re-poison fill + ~21 us of tiny graph dispatches).
__global__ __launch_bounds__(256) void mtf_kernel(const float* __restrict__ X,
                                                  float* __restrict__ out) {
    __shared__ int   bins[W];
    __shared__ int   hist[NB * NB];
    __shared__ int   rowsum[NB];
    __shared__ float probs[NB * NB];
    __shared__ float redmin[4], redmax[4];

    const int tid = threadIdx.x;
    const int s   = blockIdx.x;
    const float* xrow = X + (size_t)s * W;

    // ---- Phase 1: load + min/max reduction (wave = 64 lanes) ----
    float v = 0.0f;
    float vmin = FLT_MAX, vmax = -FLT_MAX;
    if (tid < W) { v = xrow[tid]; vmin = v; vmax = v; }
    #pragma unroll
    for (int off = 32; off >= 1; off >>= 1) {
        vmin = fminf(vmin, __shfl_down(vmin, off, 64));
        vmax = fmaxf(vmax, __shfl_down(vmax, off, 64));
    }
    if ((tid & 63) == 0) { redmin[tid >> 6] = vmin; redmax[tid >> 6] = vmax; }

    // zero histogram + rowsums while reduction lands
    for (int i = tid; i < NB * NB; i += 256) hist[i] = 0;
    if (tid < NB) rowsum[tid] = 0;
    __syncthreads();

    const float mn = fminf(fminf(redmin[0], redmin[1]), fminf(redmin[2], redmin[3]));
    const float mx = fmaxf(fmaxf(redmax[0], redmax[1]), fmaxf(redmax[2], redmax[3]));
    const float d  = (mx - mn) + 1e-6f;   // matches (X_max - X_min + EPS) in fp32

    // ---- Phase 2: bucketize (searchsorted side='left': #{edge < x}) ----
    if (tid < W) {
        float q   = (v - mn) / d;
        float xsc = q * 2.0f - 1.0f;
        double xd = (double)xsc;
        int b = 0;
        #pragma unroll
        for (int k = 1; k <= NB - 1; ++k) {
            double bk = -1.0 + 0.04 * (double)k;   // linspace inner edges (fp64)
            b += (bk < xd) ? 1 : 0;
        }
        bins[tid] = b;
    }
    __syncthreads();

    // ---- Phase 3: transition histogram + row sums (LDS atomics) ----
    if (tid < W - 1) {
        int bi = bins[tid], bj = bins[tid + 1];
        atomicAdd(&hist[bi * NB + bj], 1);
        atomicAdd(&rowsum[bi], 1);
    }
    __syncthreads();

    // ---- Phase 4: row-normalize (exact fp32 division, empty-row guard) ----
    for (int i = tid; i < NB * NB; i += 256) {
        int rs = rowsum[i / NB];
        probs[i] = (float)hist[i] / (float)(rs == 0 ? 1 : rs);
    }
    __syncthreads();

    // ---- Phase 5: gather + contiguous ascending stores (7.2 TB/s measured) ----
    float* orow = out + (size_t)s * W * W;
    const int wv   = tid >> 6;
    const int lane = tid & 63;
    const int c4   = (lane & 31) * 4;
    const int half = lane >> 5;
    const int b0 = bins[c4], b1 = bins[c4 + 1], b2 = bins[c4 + 2], b3 = bins[c4 + 3];
    #pragma unroll
    for (int it = 0; it < 16; ++it) {
        int row = (wv << 5) + (it << 1) + half;
        int rb  = bins[row] * NB;        // LDS broadcast per half-wave
        float4 o;
        o.x = probs[rb + b0];
        o.y = probs[rb + b1];
        o.z = probs[rb + b2];
        o.w = probs[rb + b3];
        *(float4*)(orow + row * W + c4) = o;
    }
}

extern "C" void kernel_launch(void* const* d_in, const int* in_sizes, int n_in,
                              void* d_out, int out_size, void* d_ws, size_t ws_size,
                              hipStream_t stream) {
    const float* X = (const float*)d_in[0];
    float* out = (float*)d_out;
    int S = in_sizes[0] / W;             // 256*6 = 1536 series
    mtf_kernel<<<dim3(S), dim3(256), 0, stream>>>(X, out);
}